// Round 8
// baseline (262.572 us; speedup 1.0000x reference)
//
#include <hip/hip_runtime.h>
#include <hip/hip_bf16.h>

using bf16 = __hip_bfloat16;
typedef __bf16 bf16x8 __attribute__((ext_vector_type(8)));
typedef __bf16 bf16x4v __attribute__((ext_vector_type(4)));
typedef float f32x4 __attribute__((ext_vector_type(4)));

#define MFMA16(a, b, c) __builtin_amdgcn_mfma_f32_16x16x32_bf16((a), (b), (c), 0, 0, 0)

// LDS-only barrier: lgkmcnt(0) + raw s_barrier (no vmcnt drain). r15-proven
// neutral; keeps global prefetches in flight across barriers.
__device__ __forceinline__ void bar_lds() {
  asm volatile("s_waitcnt lgkmcnt(0)" ::: "memory");
  __builtin_amdgcn_s_barrier();
}

// N=65536, P=6, D=256, out=(N,27) fp32. Transposed MFMA scheme:
// A = weights (m = out-feature), B = points (n = point).
// r18 == r17 RESUBMIT (round-7 bench was an infra failure: "container
// failed twice"; no kernel signal. Same experiment, clean attribution.)
// r17: 128-thread / 2-wave blocks, 64 pts, grid 1024 -> 4 blocks/CU
// (LDS 39.4KB x4 = 158KB). Wave w owns feats [128w,+128): mt=8, nt=4.
//   - phase-C LDS reads/wave: 32KB (hb reuse x8) -> per-CU C-read bytes
//     HALVED vs r11 (the quantity that separated r16 from r11).
//   - 4 independent 2-wave barrier chains per CU (vs 2 4-wave chains):
//     chain bubbles overlap across blocks.
//   - register class unchanged vs r11 (acc[8][4]=128 AGPR, 2 waves/SIMD).
//   r13's failure mode (8-wave convoys + mt=2 -> per-pt LDS doubled) is
//   inverted on both axes. Accepted cost: W2 L2 re-reads x2 (~25% L2 peak).
// Carried: staged coalesced output, phase-C input prefetch, a2n dbuf,
// LDS-tiled prep transpose, bar_lds.
//
// ws (bf16): W1t [P][256 d1][32 k'] @0 (49152)
//            W2t [P][256 d2][256 d1] @49152 (393216)
//            W3t [P][32 r][256 d2] @442368 (49152)  r<20:W3, r==20:Wocc, else 0

__global__ void prep_kernel(const float* __restrict__ W1, const float* __restrict__ b1,
                            const float* __restrict__ W2, const float* __restrict__ W3,
                            const float* __restrict__ Wocc, __bf16* __restrict__ ws) {
  const int b = blockIdx.x;
  const int tid = threadIdx.x;
  if (b < 96) {
    __shared__ float tile[64][65];  // +1 pad: transposed reads ~2-way max
    const int p = b >> 4, t = b & 15;
    const int d0 = (t >> 2) * 64, e0 = (t & 3) * 64;
    const int lane = tid & 63, grp = tid >> 6;
    const float* src = W2 + p * 65536 + (d0 + grp * 16) * 256 + e0 + lane;
#pragma unroll
    for (int i = 0; i < 16; ++i) tile[grp * 16 + i][lane] = src[i * 256];
    __syncthreads();
#pragma unroll
    for (int q = 0; q < 2; ++q) {
      const int m = tid + q * 256;     // 0..511
      const int ee = m >> 3, c = m & 7;
      bf16x8 v;
#pragma unroll
      for (int j = 0; j < 8; ++j) v[j] = (__bf16)tile[c * 8 + j][ee];
      *reinterpret_cast<bf16x8*>(
          &ws[49152 + p * 65536 + (e0 + ee) * 256 + d0 + c * 8]) = v;
    }
    return;
  }
  const int t = 49152 + (b - 96) * 256 + tid;
  if (t < 55296) {  // W1t (reordered features, b1 at k=17)
    const int u = t - 49152;
    const int p = u >> 10, r = u & 1023, n = r >> 2, c = r & 3;
    bf16x8 v;
#pragma unroll
    for (int j = 0; j < 8; ++j) {
      const int k = c * 8 + j;
      float x = 0.f;
      if (k < 17) {
        const int ko = (k < 8) ? k + 3 : ((k < 11) ? k - 8 : k);
        x = W1[p * 4352 + ko * 256 + n];
      } else if (k == 17) {
        x = b1[p * 256 + n];
      }
      v[j] = (__bf16)x;
    }
    *reinterpret_cast<bf16x8*>(&ws[p * 8192 + n * 32 + c * 8]) = v;
  } else if (t < 61440) {  // W3t (W3 || Wocc || zeros)
    const int u = t - 55296;
    const int p = u >> 10, r = u & 1023, row = r >> 5, c = r & 31;
    bf16x8 v;
#pragma unroll
    for (int j = 0; j < 8; ++j) {
      const int k = c * 8 + j;
      float x = 0.f;
      if (row < 20)       x = W3[p * 5120 + k * 20 + row];
      else if (row == 20) x = Wocc[p * 256 + k];
      v[j] = (__bf16)x;
    }
    *reinterpret_cast<bf16x8*>(&ws[442368 + p * 8192 + row * 256 + c * 8]) = v;
  }
}

// Hf [pt][256 d] (32 16B-chunks/row), XOR swizzle chunk^=(pt&7): b64 writes
// 4 accesses/bank, b128 reads 8/bank (both at throughput minimum).
__global__ __launch_bounds__(128, 2) void tpose_main(
    const float* __restrict__ tpts, const float* __restrict__ bigpts,
    const float* __restrict__ viewdir, const float* __restrict__ frame,
    const float* __restrict__ b2g, const float* __restrict__ b3g,
    const float* __restrict__ boccg, const int* __restrict__ tflag,
    const __bf16* __restrict__ ws, float* __restrict__ out) {
  const __bf16* __restrict__ W1t = ws;
  const __bf16* __restrict__ W2t = ws + 49152;
  const __bf16* __restrict__ W3t = ws + 442368;

  __shared__ __align__(16) __bf16 Xf[64 * 40];     // [pt][k' pad 40]   5 KB
  __shared__ __align__(16) __bf16 Hf[64 * 256];    // swizzled         32 KB
  __shared__ float Tocc[64 * 6];                   // per-part occ    1.5 KB

  const int tid = threadIdx.x;
  const int w = tid >> 6;         // 0..1
  const int lane = tid & 63;
  const int lq = lane >> 4;
  const int ln = lane & 15;
  const int e = ln & 7;           // swizzle key (row & 7 == ln & 7 at every use)
  const int n0 = blockIdx.x * 64;

  // one-time X init: frame octet, 1.0 at slot 17, zeros 18-31
  if (tid < 64) {
    bf16x8 f8;
#pragma unroll
    for (int j = 0; j < 8; ++j) f8[j] = (__bf16)frame[j];
    *reinterpret_cast<bf16x8*>(&Xf[tid * 40]) = f8;
    bf16x8 z = {};
    z[1] = (__bf16)1.0f;  // slot 17 = constant-1 (bias feature)
    *reinterpret_cast<bf16x8*>(&Xf[tid * 40 + 16]) = z;
    bf16x8 z2 = {};
    *reinterpret_cast<bf16x8*>(&Xf[tid * 40 + 24]) = z2;
  }

  const int role = tid & 3;  // 0: tpts, 1: bigpts, 2: viewdir, 3: idle
  const float* __restrict__ dynsrc =
      (role == 0) ? tpts : (role == 1) ? bigpts : viewdir;

  // prefetch state for part 0 (2 passes x 32 pts = 64 pts)
  float pre[2][3];
  float flv[2];
#pragma unroll
  for (int pass = 0; pass < 2; ++pass) {
    const int pt = (tid >> 2) + pass * 32;
    const int base3 = (n0 + pt) * 18;  // p=0
#pragma unroll
    for (int i = 0; i < 3; ++i) pre[pass][i] = dynsrc[base3 + i];
  }
#pragma unroll
  for (int s = 0; s < 2; ++s)
    flv[s] = (tflag[(n0 + w * 32 + s * 16 + ln) * 6] != 0) ? 1.f : 0.f;

  float psum0[2][4] = {{0.f, 0.f, 0.f, 0.f}, {0.f, 0.f, 0.f, 0.f}};
  float psum1[2][4] = {{0.f, 0.f, 0.f, 0.f}, {0.f, 0.f, 0.f, 0.f}};

  for (int p = 0; p < 6; ++p) {
    // ---- Phase A: store prefetched features (pure LDS) ----
    if (role < 3) {
#pragma unroll
      for (int pass = 0; pass < 2; ++pass) {
        const int pt = (tid >> 2) + pass * 32;
#pragma unroll
        for (int i = 0; i < 3; ++i)
          Xf[pt * 40 + 8 + role * 3 + i] = (__bf16)pre[pass][i];
      }
    }

    // hoist phase-B weight loads above the barrier (in flight across bar 1)
    bf16x8 aw[8];
#pragma unroll
    for (int mt = 0; mt < 8; ++mt)
      aw[mt] = *reinterpret_cast<const bf16x8*>(
          &W1t[p * 8192 + (w * 128 + mt * 16 + ln) * 32 + lq * 8]);

    bar_lds();  // (1) X visible; prev part's phase-D Hf reads done

    // ---- Phase B: H1 = relu(W1^T X) (bias inside GEMM via slot 17) ----
    f32x4 acc[8][4];
#pragma unroll
    for (int mt = 0; mt < 8; ++mt)
#pragma unroll
      for (int nt = 0; nt < 4; ++nt) acc[mt][nt] = f32x4{0.f, 0.f, 0.f, 0.f};
#pragma unroll
    for (int nt = 0; nt < 4; ++nt) {
      const bf16x8 xb =
          *reinterpret_cast<const bf16x8*>(&Xf[(nt * 16 + ln) * 40 + lq * 8]);
#pragma unroll
      for (int mt = 0; mt < 8; ++mt) acc[mt][nt] = MFMA16(aw[mt], xb, acc[mt][nt]);
    }
#pragma unroll
    for (int mt = 0; mt < 8; ++mt) {
      const int c = w * 16 + mt * 2 + (lq >> 1);
      const int off = ((c ^ e) << 3) + (lq & 1) * 4;
#pragma unroll
      for (int nt = 0; nt < 4; ++nt) {
        bf16x4v hv;
#pragma unroll
        for (int r = 0; r < 4; ++r) hv[r] = (__bf16)fmaxf(acc[mt][nt][r], 0.f);
        *reinterpret_cast<bf16x4v*>(&Hf[(nt * 16 + ln) * 256 + off]) = hv;
      }
    }

    bar_lds();  // (2) H1 visible

    // ---- Phase C: H2 = relu(W2^T H1 + b2); b2 pre-init into acc ----
    const __bf16* __restrict__ w2p = W2t + p * 65536 + (w * 128 + ln) * 256 + lq * 8;
    bf16x8 a2[8];
#pragma unroll
    for (int mt = 0; mt < 8; ++mt)
      a2[mt] = *reinterpret_cast<const bf16x8*>(w2p + mt * 4096);
    f32x4 b2v[8];
#pragma unroll
    for (int mt = 0; mt < 8; ++mt)
      b2v[mt] = *reinterpret_cast<const f32x4*>(
          &b2g[p * 256 + w * 128 + mt * 16 + lq * 4]);

    // prefetch part p+1 inputs (issued after a2/b2v; in flight until next A)
    const int pn = (p < 5) ? p + 1 : 5;
    float fln[2];
#pragma unroll
    for (int pass = 0; pass < 2; ++pass) {
      const int pt = (tid >> 2) + pass * 32;
      const int base3 = ((n0 + pt) * 6 + pn) * 3;
#pragma unroll
      for (int i = 0; i < 3; ++i) pre[pass][i] = dynsrc[base3 + i];
    }
#pragma unroll
    for (int s = 0; s < 2; ++s)
      fln[s] = (tflag[(n0 + w * 32 + s * 16 + ln) * 6 + pn] != 0) ? 1.f : 0.f;

#pragma unroll
    for (int mt = 0; mt < 8; ++mt)
#pragma unroll
      for (int nt = 0; nt < 4; ++nt) acc[mt][nt] = b2v[mt];  // bias preload
    {
#pragma unroll
      for (int kk = 0; kk < 8; ++kk) {
        bf16x8 a2n[8];
        if (kk < 7) {
#pragma unroll
          for (int mt = 0; mt < 8; ++mt)
            a2n[mt] = *reinterpret_cast<const bf16x8*>(
                w2p + mt * 4096 + (kk + 1) * 32);
        }
#pragma unroll
        for (int nt = 0; nt < 4; ++nt) {
          const bf16x8 hb = *reinterpret_cast<const bf16x8*>(
              &Hf[(nt * 16 + ln) * 256 + (((kk * 4 + lq) ^ e) << 3)]);
#pragma unroll
          for (int mt = 0; mt < 8; ++mt) acc[mt][nt] = MFMA16(a2[mt], hb, acc[mt][nt]);
        }
#pragma unroll
        for (int mt = 0; mt < 8; ++mt) a2[mt] = a2n[mt];
      }
    }

    bar_lds();  // (3) H1 reads done before overwrite

#pragma unroll
    for (int mt = 0; mt < 8; ++mt) {
      const int c = w * 16 + mt * 2 + (lq >> 1);
      const int off = ((c ^ e) << 3) + (lq & 1) * 4;
#pragma unroll
      for (int nt = 0; nt < 4; ++nt) {
        bf16x4v hv;
#pragma unroll
        for (int r = 0; r < 4; ++r) hv[r] = (__bf16)fmaxf(acc[mt][nt][r], 0.f);
        *reinterpret_cast<bf16x4v*>(&Hf[(nt * 16 + ln) * 256 + off]) = hv;
      }
    }

    bar_lds();  // (4) H2 visible

    // ---- Phase D: raw||occ = W3^T H2 + b3; wave w -> pts [32w, 32w+32) ----
    f32x4 acc3[2][2];
    {
      float b3v[2][4];
#pragma unroll
      for (int mt = 0; mt < 2; ++mt)
#pragma unroll
        for (int r = 0; r < 4; ++r) {
          const int d = mt * 16 + lq * 4 + r;
          float v = 0.f;
          if (d < 20)       v = b3g[p * 20 + d];
          else if (d == 20) v = boccg[p];
          b3v[mt][r] = v;
        }
#pragma unroll
      for (int mt = 0; mt < 2; ++mt)
#pragma unroll
        for (int s = 0; s < 2; ++s)
#pragma unroll
          for (int r = 0; r < 4; ++r) acc3[mt][s][r] = b3v[mt][r];  // bias preload
    }
    const __bf16* __restrict__ w3p = W3t + p * 8192 + ln * 256 + lq * 8;
#pragma unroll
    for (int kk = 0; kk < 8; ++kk) {
      bf16x8 a3[2];
#pragma unroll
      for (int mt = 0; mt < 2; ++mt)
        a3[mt] = *reinterpret_cast<const bf16x8*>(w3p + mt * 4096 + kk * 32);
#pragma unroll
      for (int s = 0; s < 2; ++s) {
        const bf16x8 hb = *reinterpret_cast<const bf16x8*>(
            &Hf[(w * 32 + s * 16 + ln) * 256 + (((kk * 4 + lq) ^ e) << 3)]);
#pragma unroll
        for (int mt = 0; mt < 2; ++mt) acc3[mt][s] = MFMA16(a3[mt], hb, acc3[mt][s]);
      }
    }

    // Epilogue (bias already in acc3); occ to LDS, not global
#pragma unroll
    for (int s = 0; s < 2; ++s) {
#pragma unroll
      for (int r = 0; r < 4; ++r) psum0[s][r] += flv[s] * acc3[0][s][r];
      if (lq == 0) {
#pragma unroll
        for (int r = 0; r < 4; ++r) psum1[s][r] += flv[s] * acc3[1][s][r];
      } else if (lq == 1) {  // dim 20 = occ (r=0)
        const float occ = 1.f / (1.f + __expf(-acc3[1][s][0]));
        Tocc[(w * 32 + s * 16 + ln) * 6 + p] = flv[s] * occ;
        psum1[s][0] += flv[s] * occ;
      }
    }

    flv[0] = fln[0];
    flv[1] = fln[1];
  }  // p loop

  // ---- Coalesced output: stage 64x27 fp32 records in LDS (reuse Hf),
  // then write float4-contiguous; every 64B line written exactly once ----
  bar_lds();  // Tocc complete; all phase-D Hf reads done
  float* stage = reinterpret_cast<float*>(Hf);
  const float inv6 = 1.f / 6.f;
#pragma unroll
  for (int s = 0; s < 2; ++s) {
    const int ptl = w * 32 + s * 16 + ln;
#pragma unroll
    for (int r = 0; r < 4; ++r) stage[ptl * 27 + lq * 4 + r] = psum0[s][r] * inv6;
    if (lq == 0) {
#pragma unroll
      for (int r = 0; r < 4; ++r) stage[ptl * 27 + 16 + r] = psum1[s][r] * inv6;
    } else if (lq == 1) {
      stage[ptl * 27 + 20] = psum1[s][0] * inv6;
    }
  }
  if (tid < 64) {
#pragma unroll
    for (int pp = 0; pp < 6; ++pp) stage[tid * 27 + 21 + pp] = Tocc[tid * 6 + pp];
  }
  bar_lds();  // stage visible
  float* outp = out + (size_t)n0 * 27;
#pragma unroll
  for (int q = 0; q < 4; ++q) {
    const int m = tid + q * 128;  // 432 float4 chunks = 64*27 floats
    if (m < 432)
      *reinterpret_cast<f32x4*>(&outp[m * 4]) =
          *reinterpret_cast<const f32x4*>(&stage[m * 4]);
  }
}

extern "C" void kernel_launch(void* const* d_in, const int* in_sizes, int n_in,
                              void* d_out, int out_size, void* d_ws, size_t ws_size,
                              hipStream_t stream) {
  const float* tpts    = (const float*)d_in[0];
  const float* bigpts  = (const float*)d_in[1];
  const float* viewdir = (const float*)d_in[2];
  const float* frame   = (const float*)d_in[5];
  const float* W1      = (const float*)d_in[6];
  const float* b1      = (const float*)d_in[7];
  const float* W2      = (const float*)d_in[8];
  const float* b2      = (const float*)d_in[9];
  const float* W3      = (const float*)d_in[10];
  const float* b3      = (const float*)d_in[11];
  const float* Wocc    = (const float*)d_in[12];
  const float* bocc    = (const float*)d_in[13];
  const int*   tflag   = (const int*)d_in[14];
  __bf16* ws  = (__bf16*)d_ws;
  float*  out = (float*)d_out;

  prep_kernel<<<144, 256, 0, stream>>>(W1, b1, W2, W3, Wocc, ws);
  tpose_main<<<1024, 128, 0, stream>>>(tpts, bigpts, viewdir, frame, b2, b3,
                                       bocc, tflag, ws, out);
}

// Round 9
// 182.489 us; speedup vs baseline: 1.4388x; 1.4388x over previous
//
#include <hip/hip_runtime.h>
#include <hip/hip_bf16.h>

using bf16 = __hip_bfloat16;
typedef __bf16 bf16x8 __attribute__((ext_vector_type(8)));
typedef __bf16 bf16x4v __attribute__((ext_vector_type(4)));
typedef float f32x4 __attribute__((ext_vector_type(4)));

#define MFMA16(a, b, c) __builtin_amdgcn_mfma_f32_16x16x32_bf16((a), (b), (c), 0, 0, 0)

// LDS-only barrier: lgkmcnt(0) + raw s_barrier (no vmcnt drain). r15-proven
// neutral; keeps global prefetches in flight across barriers.
__device__ __forceinline__ void bar_lds() {
  asm volatile("s_waitcnt lgkmcnt(0)" ::: "memory");
  __builtin_amdgcn_s_barrier();
}

// N=65536, P=6, D=256, out=(N,27) fp32. Transposed MFMA scheme:
// A = weights (m = out-feature), B = points (n = point). 128 pts/block,
// 256 threads (4 waves): wave w owns feats [64w,64w+64) in B/C, pts
// [32w,32w+32) in D. 2 blocks/CU (LDS 77K), 2 waves/SIMD.
// r19 (this round): r15 base (best, 112us) + two targeted changes:
//  (a) phase-C kk loop ROLLED (#pragma unroll 1) with hb split 4+4 and a
//      sched_barrier fence — r11's mt=4 LDS traffic (unchanged) but half
//      the transient pressure. Scratch meter: r15 writes 33MB vs 7 ideal
//      (~26MB spill); r16 proved rolled kk = 0 spill, but confounded with
//      mt=2 (2x LDS reads, the regression). This is the untested cell:
//      r11 shape + rolled loop.
//  (b) s_setprio(1) around the phase-C MFMA cluster (T5): 2 independent
//      block chains/CU at drifted phases = the role-diversity regime where
//      setprio paid +4-7% (attn, m191).
// Carried: staged coalesced output, phase-C input prefetch, a2n dbuf,
// LDS-tiled prep transpose, bar_lds.
//
// ws (bf16): W1t [P][256 d1][32 k'] @0 (49152)
//            W2t [P][256 d2][256 d1] @49152 (393216)
//            W3t [P][32 r][256 d2] @442368 (49152)  r<20:W3, r==20:Wocc, else 0

__global__ void prep_kernel(const float* __restrict__ W1, const float* __restrict__ b1,
                            const float* __restrict__ W2, const float* __restrict__ W3,
                            const float* __restrict__ Wocc, __bf16* __restrict__ ws) {
  const int b = blockIdx.x;
  const int tid = threadIdx.x;
  if (b < 96) {
    __shared__ float tile[64][65];  // +1 pad: transposed reads ~2-way max
    const int p = b >> 4, t = b & 15;
    const int d0 = (t >> 2) * 64, e0 = (t & 3) * 64;
    const int lane = tid & 63, grp = tid >> 6;
    const float* src = W2 + p * 65536 + (d0 + grp * 16) * 256 + e0 + lane;
#pragma unroll
    for (int i = 0; i < 16; ++i) tile[grp * 16 + i][lane] = src[i * 256];
    __syncthreads();
#pragma unroll
    for (int q = 0; q < 2; ++q) {
      const int m = tid + q * 256;     // 0..511
      const int ee = m >> 3, c = m & 7;
      bf16x8 v;
#pragma unroll
      for (int j = 0; j < 8; ++j) v[j] = (__bf16)tile[c * 8 + j][ee];
      *reinterpret_cast<bf16x8*>(
          &ws[49152 + p * 65536 + (e0 + ee) * 256 + d0 + c * 8]) = v;
    }
    return;
  }
  const int t = 49152 + (b - 96) * 256 + tid;
  if (t < 55296) {  // W1t (reordered features, b1 at k=17)
    const int u = t - 49152;
    const int p = u >> 10, r = u & 1023, n = r >> 2, c = r & 3;
    bf16x8 v;
#pragma unroll
    for (int j = 0; j < 8; ++j) {
      const int k = c * 8 + j;
      float x = 0.f;
      if (k < 17) {
        const int ko = (k < 8) ? k + 3 : ((k < 11) ? k - 8 : k);
        x = W1[p * 4352 + ko * 256 + n];
      } else if (k == 17) {
        x = b1[p * 256 + n];
      }
      v[j] = (__bf16)x;
    }
    *reinterpret_cast<bf16x8*>(&ws[p * 8192 + n * 32 + c * 8]) = v;
  } else if (t < 61440) {  // W3t (W3 || Wocc || zeros)
    const int u = t - 55296;
    const int p = u >> 10, r = u & 1023, row = r >> 5, c = r & 31;
    bf16x8 v;
#pragma unroll
    for (int j = 0; j < 8; ++j) {
      const int k = c * 8 + j;
      float x = 0.f;
      if (row < 20)       x = W3[p * 5120 + k * 20 + row];
      else if (row == 20) x = Wocc[p * 256 + k];
      v[j] = (__bf16)x;
    }
    *reinterpret_cast<bf16x8*>(&ws[442368 + p * 8192 + row * 256 + c * 8]) = v;
  }
}

// Hf [pt][256 d] (32 16B-chunks/row), XOR swizzle chunk^=(pt&7): b64 writes
// 4 accesses/bank, b128 reads 8/bank (both at throughput minimum).
__global__ __launch_bounds__(256, 2) void tpose_main(
    const float* __restrict__ tpts, const float* __restrict__ bigpts,
    const float* __restrict__ viewdir, const float* __restrict__ frame,
    const float* __restrict__ b2g, const float* __restrict__ b3g,
    const float* __restrict__ boccg, const int* __restrict__ tflag,
    const __bf16* __restrict__ ws, float* __restrict__ out) {
  const __bf16* __restrict__ W1t = ws;
  const __bf16* __restrict__ W2t = ws + 49152;
  const __bf16* __restrict__ W3t = ws + 442368;

  __shared__ __align__(16) __bf16 Xf[128 * 40];    // [pt][k' pad 40]  10 KB
  __shared__ __align__(16) __bf16 Hf[128 * 256];   // swizzled         64 KB
  __shared__ float Tocc[128 * 6];                  // per-part occ      3 KB

  const int tid = threadIdx.x;
  const int w = tid >> 6;
  const int lane = tid & 63;
  const int lq = lane >> 4;
  const int ln = lane & 15;
  const int e = ln & 7;           // swizzle key (row & 7 == ln & 7 at every use)
  const int n0 = blockIdx.x * 128;

  // one-time X init: frame octet, 1.0 at slot 17, zeros 18-31
  if (tid < 128) {
    bf16x8 f8;
#pragma unroll
    for (int j = 0; j < 8; ++j) f8[j] = (__bf16)frame[j];
    *reinterpret_cast<bf16x8*>(&Xf[tid * 40]) = f8;
    bf16x8 z = {};
    z[1] = (__bf16)1.0f;  // slot 17 = constant-1 (bias feature)
    *reinterpret_cast<bf16x8*>(&Xf[tid * 40 + 16]) = z;
    bf16x8 z2 = {};
    *reinterpret_cast<bf16x8*>(&Xf[tid * 40 + 24]) = z2;
  }

  const int role = tid & 3;  // 0: tpts, 1: bigpts, 2: viewdir, 3: idle
  const float* __restrict__ dynsrc =
      (role == 0) ? tpts : (role == 1) ? bigpts : viewdir;

  // prefetch state for part 0
  float pre[2][3];
  float flv[2];
#pragma unroll
  for (int pass = 0; pass < 2; ++pass) {
    const int pt = (tid >> 2) + pass * 64;
    const int base3 = (n0 + pt) * 18;  // p=0
#pragma unroll
    for (int i = 0; i < 3; ++i) pre[pass][i] = dynsrc[base3 + i];
  }
#pragma unroll
  for (int s = 0; s < 2; ++s)
    flv[s] = (tflag[(n0 + w * 32 + s * 16 + ln) * 6] != 0) ? 1.f : 0.f;

  float psum0[2][4] = {{0.f, 0.f, 0.f, 0.f}, {0.f, 0.f, 0.f, 0.f}};
  float psum1[2][4] = {{0.f, 0.f, 0.f, 0.f}, {0.f, 0.f, 0.f, 0.f}};

  for (int p = 0; p < 6; ++p) {
    // ---- Phase A: store prefetched features (pure LDS) ----
    if (role < 3) {
#pragma unroll
      for (int pass = 0; pass < 2; ++pass) {
        const int pt = (tid >> 2) + pass * 64;
#pragma unroll
        for (int i = 0; i < 3; ++i)
          Xf[pt * 40 + 8 + role * 3 + i] = (__bf16)pre[pass][i];
      }
    }

    // hoist phase-B weight loads above the barrier (in flight across bar 1)
    bf16x8 aw[4];
#pragma unroll
    for (int mt = 0; mt < 4; ++mt)
      aw[mt] = *reinterpret_cast<const bf16x8*>(
          &W1t[p * 8192 + (w * 64 + mt * 16 + ln) * 32 + lq * 8]);

    bar_lds();  // (1) X visible; prev part's phase-D Hf reads done

    // ---- Phase B: H1 = relu(W1^T X) (bias inside GEMM via slot 17) ----
    f32x4 acc[4][8];
#pragma unroll
    for (int mt = 0; mt < 4; ++mt)
#pragma unroll
      for (int nt = 0; nt < 8; ++nt) acc[mt][nt] = f32x4{0.f, 0.f, 0.f, 0.f};
#pragma unroll
    for (int nt = 0; nt < 8; ++nt) {
      const bf16x8 xb =
          *reinterpret_cast<const bf16x8*>(&Xf[(nt * 16 + ln) * 40 + lq * 8]);
#pragma unroll
      for (int mt = 0; mt < 4; ++mt) acc[mt][nt] = MFMA16(aw[mt], xb, acc[mt][nt]);
    }
#pragma unroll
    for (int mt = 0; mt < 4; ++mt) {
      const int c = w * 8 + mt * 2 + (lq >> 1);
      const int off = ((c ^ e) << 3) + (lq & 1) * 4;
#pragma unroll
      for (int nt = 0; nt < 8; ++nt) {
        bf16x4v hv;
#pragma unroll
        for (int r = 0; r < 4; ++r) hv[r] = (__bf16)fmaxf(acc[mt][nt][r], 0.f);
        *reinterpret_cast<bf16x4v*>(&Hf[(nt * 16 + ln) * 256 + off]) = hv;
      }
    }

    bar_lds();  // (2) H1 visible

    // ---- Phase C: H2 = relu(W2^T H1 + b2); b2 pre-init into acc ----
    const __bf16* __restrict__ w2p = W2t + p * 65536 + (w * 64 + ln) * 256 + lq * 8;
    bf16x8 a2[4];
#pragma unroll
    for (int mt = 0; mt < 4; ++mt)
      a2[mt] = *reinterpret_cast<const bf16x8*>(w2p + mt * 4096);
    f32x4 b2v[4];
#pragma unroll
    for (int mt = 0; mt < 4; ++mt)
      b2v[mt] = *reinterpret_cast<const f32x4*>(
          &b2g[p * 256 + w * 64 + mt * 16 + lq * 4]);

    // prefetch part p+1 inputs (issued after a2/b2v; in flight until next A)
    const int pn = (p < 5) ? p + 1 : 5;
    float fln[2];
#pragma unroll
    for (int pass = 0; pass < 2; ++pass) {
      const int pt = (tid >> 2) + pass * 64;
      const int base3 = ((n0 + pt) * 6 + pn) * 3;
#pragma unroll
      for (int i = 0; i < 3; ++i) pre[pass][i] = dynsrc[base3 + i];
    }
#pragma unroll
    for (int s = 0; s < 2; ++s)
      fln[s] = (tflag[(n0 + w * 32 + s * 16 + ln) * 6 + pn] != 0) ? 1.f : 0.f;

#pragma unroll
    for (int mt = 0; mt < 4; ++mt)
#pragma unroll
      for (int nt = 0; nt < 8; ++nt) acc[mt][nt] = b2v[mt];  // bias preload

    // ROLLED kk loop (r16-proven spill-free pattern) at r11's mt=4 reuse:
    // transient set = a2n[4] (16) + hb[4] (16) instead of the full-unroll
    // hoist; LDS read count unchanged vs r11.
    __builtin_amdgcn_s_setprio(1);
#pragma unroll 1
    for (int kk = 0; kk < 8; ++kk) {
      bf16x8 a2n[4];
      if (kk < 7) {  // uniform branch; dbuf next-kk weights (issued early)
#pragma unroll
        for (int mt = 0; mt < 4; ++mt)
          a2n[mt] = *reinterpret_cast<const bf16x8*>(
              w2p + mt * 4096 + (kk + 1) * 32);
      }
      const int off = ((kk * 4 + lq) ^ e) << 3;
      // half 0: nt 0..3
      {
        bf16x8 hb[4];
#pragma unroll
        for (int nt = 0; nt < 4; ++nt)
          hb[nt] = *reinterpret_cast<const bf16x8*>(
              &Hf[(nt * 16 + ln) * 256 + off]);
#pragma unroll
        for (int nt = 0; nt < 4; ++nt)
#pragma unroll
          for (int mt = 0; mt < 4; ++mt)
            acc[mt][nt] = MFMA16(a2[mt], hb[nt], acc[mt][nt]);
      }
      __builtin_amdgcn_sched_barrier(0);  // fence: keep half-1 loads below
      // half 1: nt 4..7
      {
        bf16x8 hb[4];
#pragma unroll
        for (int nt = 0; nt < 4; ++nt)
          hb[nt] = *reinterpret_cast<const bf16x8*>(
              &Hf[((nt + 4) * 16 + ln) * 256 + off]);
#pragma unroll
        for (int nt = 0; nt < 4; ++nt)
#pragma unroll
          for (int mt = 0; mt < 4; ++mt)
            acc[mt][nt + 4] = MFMA16(a2[mt], hb[nt], acc[mt][nt + 4]);
      }
#pragma unroll
      for (int mt = 0; mt < 4; ++mt) a2[mt] = a2n[mt];
    }
    __builtin_amdgcn_s_setprio(0);

    bar_lds();  // (3) H1 reads done before overwrite

#pragma unroll
    for (int mt = 0; mt < 4; ++mt) {
      const int c = w * 8 + mt * 2 + (lq >> 1);
      const int off = ((c ^ e) << 3) + (lq & 1) * 4;
#pragma unroll
      for (int nt = 0; nt < 8; ++nt) {
        bf16x4v hv;
#pragma unroll
        for (int r = 0; r < 4; ++r) hv[r] = (__bf16)fmaxf(acc[mt][nt][r], 0.f);
        *reinterpret_cast<bf16x4v*>(&Hf[(nt * 16 + ln) * 256 + off]) = hv;
      }
    }

    bar_lds();  // (4) H2 visible

    // ---- Phase D: raw||occ = W3^T H2 + b3; wave w -> pts [32w, 32w+32) ----
    f32x4 acc3[2][2];
    {
      float b3v[2][4];
#pragma unroll
      for (int mt = 0; mt < 2; ++mt)
#pragma unroll
        for (int r = 0; r < 4; ++r) {
          const int d = mt * 16 + lq * 4 + r;
          float v = 0.f;
          if (d < 20)       v = b3g[p * 20 + d];
          else if (d == 20) v = boccg[p];
          b3v[mt][r] = v;
        }
#pragma unroll
      for (int mt = 0; mt < 2; ++mt)
#pragma unroll
        for (int s = 0; s < 2; ++s)
#pragma unroll
          for (int r = 0; r < 4; ++r) acc3[mt][s][r] = b3v[mt][r];  // bias preload
    }
    const __bf16* __restrict__ w3p = W3t + p * 8192 + ln * 256 + lq * 8;
#pragma unroll
    for (int kk = 0; kk < 8; ++kk) {
      bf16x8 a3[2];
#pragma unroll
      for (int mt = 0; mt < 2; ++mt)
        a3[mt] = *reinterpret_cast<const bf16x8*>(w3p + mt * 4096 + kk * 32);
#pragma unroll
      for (int s = 0; s < 2; ++s) {
        const bf16x8 hb = *reinterpret_cast<const bf16x8*>(
            &Hf[(w * 32 + s * 16 + ln) * 256 + (((kk * 4 + lq) ^ e) << 3)]);
#pragma unroll
        for (int mt = 0; mt < 2; ++mt) acc3[mt][s] = MFMA16(a3[mt], hb, acc3[mt][s]);
      }
    }

    // Epilogue (bias already in acc3); occ to LDS, not global
#pragma unroll
    for (int s = 0; s < 2; ++s) {
#pragma unroll
      for (int r = 0; r < 4; ++r) psum0[s][r] += flv[s] * acc3[0][s][r];
      if (lq == 0) {
#pragma unroll
        for (int r = 0; r < 4; ++r) psum1[s][r] += flv[s] * acc3[1][s][r];
      } else if (lq == 1) {  // dim 20 = occ (r=0)
        const float occ = 1.f / (1.f + __expf(-acc3[1][s][0]));
        Tocc[(w * 32 + s * 16 + ln) * 6 + p] = flv[s] * occ;
        psum1[s][0] += flv[s] * occ;
      }
    }

    flv[0] = fln[0];
    flv[1] = fln[1];
  }  // p loop

  // ---- Coalesced output: stage 128x27 fp32 records in LDS (reuse Hf),
  // then write float4-contiguous; every 64B line written exactly once ----
  bar_lds();  // Tocc complete; all phase-D Hf reads done
  float* stage = reinterpret_cast<float*>(Hf);
  const float inv6 = 1.f / 6.f;
#pragma unroll
  for (int s = 0; s < 2; ++s) {
    const int ptl = w * 32 + s * 16 + ln;
#pragma unroll
    for (int r = 0; r < 4; ++r) stage[ptl * 27 + lq * 4 + r] = psum0[s][r] * inv6;
    if (lq == 0) {
#pragma unroll
      for (int r = 0; r < 4; ++r) stage[ptl * 27 + 16 + r] = psum1[s][r] * inv6;
    } else if (lq == 1) {
      stage[ptl * 27 + 20] = psum1[s][0] * inv6;
    }
  }
  if (tid < 128) {
#pragma unroll
    for (int pp = 0; pp < 6; ++pp) stage[tid * 27 + 21 + pp] = Tocc[tid * 6 + pp];
  }
  bar_lds();  // stage visible
  float* outp = out + (size_t)n0 * 27;
#pragma unroll
  for (int q = 0; q < 4; ++q) {
    const int m = tid + q * 256;  // 864 float4 chunks = 128*27 floats
    if (m < 864)
      *reinterpret_cast<f32x4*>(&outp[m * 4]) =
          *reinterpret_cast<const f32x4*>(&stage[m * 4]);
  }
}

extern "C" void kernel_launch(void* const* d_in, const int* in_sizes, int n_in,
                              void* d_out, int out_size, void* d_ws, size_t ws_size,
                              hipStream_t stream) {
  const float* tpts    = (const float*)d_in[0];
  const float* bigpts  = (const float*)d_in[1];
  const float* viewdir = (const float*)d_in[2];
  const float* frame   = (const float*)d_in[5];
  const float* W1      = (const float*)d_in[6];
  const float* b1      = (const float*)d_in[7];
  const float* W2      = (const float*)d_in[8];
  const float* b2      = (const float*)d_in[9];
  const float* W3      = (const float*)d_in[10];
  const float* b3      = (const float*)d_in[11];
  const float* Wocc    = (const float*)d_in[12];
  const float* bocc    = (const float*)d_in[13];
  const int*   tflag   = (const int*)d_in[14];
  __bf16* ws  = (__bf16*)d_ws;
  float*  out = (float*)d_out;

  prep_kernel<<<144, 256, 0, stream>>>(W1, b1, W2, W3, Wocc, ws);
  tpose_main<<<512, 256, 0, stream>>>(tpts, bigpts, viewdir, frame, b2, b3,
                                      bocc, tflag, ws, out);
}